// Round 2
// baseline (440.515 us; speedup 1.0000x reference)
//
#include <hip/hip_runtime.h>

// B=32, S1=S2=14, NC=2, DC=16, F=32, I=8
// rows = 200704, each row an F x I = 32 x 8 tile; de = row & 31 picks the
// (d,e) weight slice. Outputs: [C | U_hat_I], each rows*256 fp32.
#define N_ROWS      200704
#define ROW_ELEMS   256
#define C_ELEMS     51380224LL
#define BLOCKS      2048
#define WAVES_PER_BLOCK 4
#define TOTAL_WAVES (BLOCKS * WAVES_PER_BLOCK)   // 8192; multiple of 32 =>
                                                 // de is CONSTANT per wave.

__global__ __launch_bounds__(256) void mhsa_softmax_kernel(
    const float* __restrict__ U_hat,     // [rows][32]
    const float* __restrict__ W_t,       // [32][32][8]  (de, f, i)
    const float* __restrict__ W_affine,  // [32][32][8]
    float* __restrict__ out)             // [C | U_hat_I]
{
    const int lane = threadIdx.x & 63;
    const int wid  = blockIdx.x * WAVES_PER_BLOCK + (threadIdx.x >> 6);
    // lane owns i = lane&7, f = (lane>>3) + 8j; in-row offset = lane + 64j
    // -> every weight load / output store is a fully-coalesced 256B access.
    const int fg = lane >> 3;
    const int de = wid & 31;             // invariant across the row loop

    const float* wa = W_affine + de * ROW_ELEMS;
    const float* wt = W_t      + de * ROW_ELEMS;

    // Weights loaded ONCE per wave.
    float wav[4], wtv[4];
#pragma unroll
    for (int j = 0; j < 4; ++j) {
        wav[j] = wa[64 * j + lane];
        wtv[j] = wt[64 * j + lane];
    }
    // Hoisted per-i max_f of W_t. Valid because diag >= 0 (sum of squares),
    // so max_f(diag*wt) = diag * max_f(wt).
    float wtmax = fmaxf(fmaxf(wtv[0], wtv[1]), fmaxf(wtv[2], wtv[3]));
    wtmax = fmaxf(wtmax, __shfl_xor(wtmax, 8));
    wtmax = fmaxf(wtmax, __shfl_xor(wtmax, 16));
    wtmax = fmaxf(wtmax, __shfl_xor(wtmax, 32));

    // ---- Software-pipelined row loop (prefetch depth 1) ----
    // Next row's U_hat loads are issued BEFORE this row's 8 stores, so the
    // s_waitcnt consuming them is vmcnt(8) instead of vmcnt(0): stores are
    // never drained inside the loop and stream at full depth (~7 rows of
    // stores in flight per wave under the vmcnt cap).
    int r = wid;                          // wid < 8192 <= N_ROWS: always valid
    float u[4];
    {
        const float* uh = U_hat + (long long)r * 32;
#pragma unroll
        for (int j = 0; j < 4; ++j)
            u[j] = __builtin_nontemporal_load(uh + fg + 8 * j);
    }

    while (r < N_ROWS) {
        const int rn = r + TOTAL_WAVES;                    // wave-uniform
        const int rp = (rn < N_ROWS) ? rn : r;             // clamped: always valid
        float un[4];
        {
            const float* uhn = U_hat + (long long)rp * 32;
#pragma unroll
            for (int j = 0; j < 4; ++j)
                un[j] = __builtin_nontemporal_load(uhn + fg + 8 * j);
        }

        float* outC = out + (long long)r * ROW_ELEMS;
        float* outU = out + C_ELEMS + (long long)r * ROW_ELEMS;

        float uhi[4];
        float sq = 0.f;
#pragma unroll
        for (int j = 0; j < 4; ++j) {
            uhi[j] = u[j] * wav[j];
            __builtin_nontemporal_store(uhi[j], outU + 64 * j + lane);
            sq = fmaf(uhi[j], uhi[j], sq);
        }
        sq += __shfl_xor(sq, 8);
        sq += __shfl_xor(sq, 16);
        sq += __shfl_xor(sq, 32);
        const float diag = sq * 0.25f;      // / sqrt(16)
        const float m    = diag * wtmax;    // exact softmax max

        float e[4], s = 0.f;
#pragma unroll
        for (int j = 0; j < 4; ++j) {
            e[j] = __expf(fmaf(diag, wtv[j], -m));
            s += e[j];
        }
        s += __shfl_xor(s, 8);
        s += __shfl_xor(s, 16);
        s += __shfl_xor(s, 32);
        const float inv = __builtin_amdgcn_rcpf(s);  // s in (0,32], safe

#pragma unroll
        for (int j = 0; j < 4; ++j)
            __builtin_nontemporal_store(e[j] * inv, outC + 64 * j + lane);

        // rotate pipeline (on the final iteration un == u; loop then exits)
#pragma unroll
        for (int j = 0; j < 4; ++j) u[j] = un[j];
        r = rn;
    }
}

extern "C" void kernel_launch(void* const* d_in, const int* in_sizes, int n_in,
                              void* d_out, int out_size, void* d_ws, size_t ws_size,
                              hipStream_t stream) {
    const float* U_hat    = (const float*)d_in[0];
    const float* W_t      = (const float*)d_in[1];
    const float* W_affine = (const float*)d_in[2];
    float* out = (float*)d_out;

    mhsa_softmax_kernel<<<BLOCKS, 256, 0, stream>>>(U_hat, W_t, W_affine, out);
}

// Round 3
// 431.673 us; speedup vs baseline: 1.0205x; 1.0205x over previous
//
#include <hip/hip_runtime.h>

// B=32, S1=S2=14, NC=2, DC=16, F=32, I=8
// rows = 200704, each row an F x I = 32 x 8 tile; de = row & 31 picks the
// (d,e) weight slice. Outputs: [C | U_hat_I], each rows*256 fp32.
//
// Lane layout (v3): lane owns TWO float2 slots per output row:
//   oA = 2*lane       -> (f = lane>>2,      i = 2*(lane&3) + {0,1})
//   oB = 2*lane + 128 -> (f = lane>>2 + 16, same i pair)
// => every store is global_store_dwordx2, 512B contiguous per wave-instr
//    (full cache lines -> no RFO write amplification), and f-reductions are
//    4 shuffle rounds (xor 4,8,16,32) over the 16-lane group sharing an i-pair.
#define N_ROWS      200704
#define ROW_ELEMS   256
#define C_ELEMS     51380224LL
#define BLOCKS      2048
#define WAVES_PER_BLOCK 4
#define TOTAL_WAVES (BLOCKS * WAVES_PER_BLOCK)   // 8192; multiple of 32 =>
                                                 // de is CONSTANT per wave.

__global__ __launch_bounds__(256) void mhsa_softmax_kernel(
    const float* __restrict__ U_hat,     // [rows][32]
    const float* __restrict__ W_t,       // [32][32][8]  (de, f, i)
    const float* __restrict__ W_affine,  // [32][32][8]
    float* __restrict__ out)             // [C | U_hat_I]
{
    const int lane = threadIdx.x & 63;
    const int wid  = blockIdx.x * WAVES_PER_BLOCK + (threadIdx.x >> 6);
    const int q    = lane >> 2;          // fA = q, fB = q + 16
    const int de   = wid & 31;           // invariant across the row loop

    const float* wa = W_affine + de * ROW_ELEMS;
    const float* wt = W_t      + de * ROW_ELEMS;

    const int oA = 2 * lane;             // (fA, i0..i0+1)
    const int oB = 2 * lane + 128;       // (fB, i0..i0+1)

    // Weights loaded ONCE per wave, as dwordx2.
    const float2 wavA = *(const float2*)(wa + oA);
    const float2 wavB = *(const float2*)(wa + oB);
    const float2 wtvA = *(const float2*)(wt + oA);
    const float2 wtvB = *(const float2*)(wt + oB);

    // Hoisted per-i max_f of W_t (valid: diag >= 0, so max_f(diag*wt) =
    // diag * max_f(wt)). Local max over {fA,fB}, then 16-lane butterfly.
    float wtm0 = fmaxf(wtvA.x, wtvB.x);
    float wtm1 = fmaxf(wtvA.y, wtvB.y);
#pragma unroll
    for (int msk = 4; msk <= 32; msk <<= 1) {
        wtm0 = fmaxf(wtm0, __shfl_xor(wtm0, msk));
        wtm1 = fmaxf(wtm1, __shfl_xor(wtm1, msk));
    }

    // Depth-1 prefetch of the two U_hat words this lane needs.
    int r = wid;                          // wid < 8192 <= N_ROWS: always valid
    float uA, uB;
    {
        const float* uh = U_hat + (long long)r * 32;
        uA = uh[q];
        uB = uh[q + 16];
    }

    while (r < N_ROWS) {
        const int rn = r + TOTAL_WAVES;                 // wave-uniform
        const int rp = (rn < N_ROWS) ? rn : r;          // clamped: always valid
        const float* uhn = U_hat + (long long)rp * 32;
        const float uAn = uhn[q];
        const float uBn = uhn[q + 16];

        float* outC = out + (long long)r * ROW_ELEMS;
        float* outU = out + C_ELEMS + (long long)r * ROW_ELEMS;

        // U_hat_I = u * W_affine, stored as two dwordx2 per lane.
        float2 uhiA, uhiB;
        uhiA.x = uA * wavA.x;  uhiA.y = uA * wavA.y;
        uhiB.x = uB * wavB.x;  uhiB.y = uB * wavB.y;
        *(float2*)(outU + oA) = uhiA;
        *(float2*)(outU + oB) = uhiB;

        // diag[i] = sum_f uhi^2 / 4: local fold over {fA,fB}, then butterfly.
        float p0 = fmaf(uhiA.x, uhiA.x, uhiB.x * uhiB.x);
        float p1 = fmaf(uhiA.y, uhiA.y, uhiB.y * uhiB.y);
#pragma unroll
        for (int msk = 4; msk <= 32; msk <<= 1) {
            p0 += __shfl_xor(p0, msk);
            p1 += __shfl_xor(p1, msk);
        }
        const float d0 = p0 * 0.25f;       // / sqrt(16)
        const float d1 = p1 * 0.25f;
        const float m0 = d0 * wtm0;        // exact softmax max per i
        const float m1 = d1 * wtm1;

        const float eAx = __expf(fmaf(d0, wtvA.x, -m0));
        const float eAy = __expf(fmaf(d1, wtvA.y, -m1));
        const float eBx = __expf(fmaf(d0, wtvB.x, -m0));
        const float eBy = __expf(fmaf(d1, wtvB.y, -m1));

        float s0 = eAx + eBx;
        float s1 = eAy + eBy;
#pragma unroll
        for (int msk = 4; msk <= 32; msk <<= 1) {
            s0 += __shfl_xor(s0, msk);
            s1 += __shfl_xor(s1, msk);
        }
        const float inv0 = __builtin_amdgcn_rcpf(s0);   // s in (0,32], safe
        const float inv1 = __builtin_amdgcn_rcpf(s1);

        float2 cA, cB;
        cA.x = eAx * inv0;  cA.y = eAy * inv1;
        cB.x = eBx * inv0;  cB.y = eBy * inv1;
        *(float2*)(outC + oA) = cA;
        *(float2*)(outC + oB) = cB;

        // rotate pipeline (final iteration: un == u; loop then exits)
        uA = uAn;
        uB = uBn;
        r = rn;
    }
}

extern "C" void kernel_launch(void* const* d_in, const int* in_sizes, int n_in,
                              void* d_out, int out_size, void* d_ws, size_t ws_size,
                              hipStream_t stream) {
    const float* U_hat    = (const float*)d_in[0];
    const float* W_t      = (const float*)d_in[1];
    const float* W_affine = (const float*)d_in[2];
    float* out = (float*)d_out;

    mhsa_softmax_kernel<<<BLOCKS, 256, 0, stream>>>(U_hat, W_t, W_affine, out);
}